// Round 3
// baseline (470.820 us; speedup 1.0000x reference)
//
#include <hip/hip_runtime.h>
#include <math.h>

// Problem constants
constexpr int Bb = 8;     // batch
constexpr int Ns = 1024;  // tokens (32x32)
constexpr int Es = 256;   // embed
constexpr int NH = 8;     // heads
constexpr int DH = 32;    // head dim
constexpr int Mrows = Bb * Ns;        // 8192
constexpr int NX = Mrows * Es;        // 2097152
constexpr int NQ = 3 * Es * Es;       // 196608
constexpr int NP = Es * Es;           // 65536

constexpr int CAST_UNITS = (NX + NQ + NP) / (8 * 256);  // 1152
constexpr int QKV_TILES  = 1536;                        // 128 m-tiles x 12 j-tiles
constexpr int ATTN_TILES = Bb * NH * 32;                // 2048
constexpr int PROJ_TILES = 512;                         // 128 m-tiles x 4 j-tiles

// 4 blocks/CU x 256 CU. Co-residency is a compile-time contract:
// measured VGPR_Count=56 (R2) << 128 cap from __launch_bounds__(256,4),
// LDS 18432B x 4 = 73.7KB < 160KB. Both limits admit 4 blocks/CU.
constexpr int GRID = 1024;
constexpr int NGRP = 8;              // barrier groups ~ XCDs (blockIdx&7)
constexpr int GRPSZ = GRID / NGRP;   // 128 arrivals per group

typedef __bf16 bf16x8 __attribute__((ext_vector_type(8)));
typedef float  f32x4  __attribute__((ext_vector_type(4)));
union U4B8 { uint4 u; bf16x8 b; unsigned short s[8]; };

__device__ __forceinline__ unsigned short f2bf(float f) {
    union { float f; unsigned u; } c; c.f = f;
    unsigned r = (c.u + 0x7FFFu + ((c.u >> 16) & 1u)) >> 16;
    return (unsigned short)r;
}
__device__ __forceinline__ float bf2f(unsigned short h) {
    union { unsigned u; float f; } c; c.u = ((unsigned)h) << 16;
    return c.f;
}

#define GLD 72    // gemm LDS row stride (bf16)
#define PST 232   // attn P row stride (bf16)

// ---------------------------------------------------------------------------
// Hierarchical device-scope barrier (R2 post-mortem fix).
// R2 measured ~67us/barrier: 512 cross-XCD RMWs on ONE line that waiters were
// simultaneously acquire-polling -> line thrash. New layout, all on separate
// 128B lines (u32 indices into a zeroed region):
//   B[g*32]  g=0..7 : per-group arrival counters (blockIdx&7 ~ XCD-local)
//   B[256]           : master counter (8 arrivals only)
//   B[288]           : generation word (write-once per barrier, read-shared)
// Release-sequence chain: group leader resets its counter, acq_rel RMW on
// master publishes it; final master block's release store on gen publishes
// everything; waiters acquire gen. Poll MUST be agent-scope acquire (relaxed
// loads can spin forever on a stale non-coherent XCD L2 line).
// Spin bounded (~0.1s): pathological case = wrong answer, never a dead container.
// ---------------------------------------------------------------------------
__device__ __forceinline__ void grid_barrier(unsigned* B) {
    __syncthreads();
    if (threadIdx.x == 0) {
        __threadfence();
        unsigned* gcnt   = B + (blockIdx.x & (NGRP - 1)) * 32;
        unsigned* master = B + 256;
        unsigned* gen    = B + 288;
        unsigned g = __hip_atomic_load(gen, __ATOMIC_RELAXED, __HIP_MEMORY_SCOPE_AGENT);
        unsigned a = __hip_atomic_fetch_add(gcnt, 1u, __ATOMIC_ACQ_REL, __HIP_MEMORY_SCOPE_AGENT);
        bool done = false;
        if (a == GRPSZ - 1u) {
            __hip_atomic_store(gcnt, 0u, __ATOMIC_RELAXED, __HIP_MEMORY_SCOPE_AGENT);
            unsigned m = __hip_atomic_fetch_add(master, 1u, __ATOMIC_ACQ_REL, __HIP_MEMORY_SCOPE_AGENT);
            if (m == NGRP - 1u) {
                __hip_atomic_store(master, 0u, __ATOMIC_RELAXED, __HIP_MEMORY_SCOPE_AGENT);
                __hip_atomic_store(gen, g + 1u, __ATOMIC_RELEASE, __HIP_MEMORY_SCOPE_AGENT);
                done = true;
            }
        }
        if (!done) {
            unsigned spins = 0;
            while (__hip_atomic_load(gen, __ATOMIC_ACQUIRE, __HIP_MEMORY_SCOPE_AGENT) == g) {
                __builtin_amdgcn_s_sleep(2);
                if (++spins > (1u << 18)) break;   // ~0.1s tripwire
            }
        }
        __threadfence();
    }
    __syncthreads();
}

// ---------------------------------------------------------------------------
// Persistent mega-kernel: cast -> [bar] -> qkv -> [bar] -> attn -> [bar] -> proj.
// Phase inner loops byte-identical to the harness-verified 4-kernel version.
// LDS: qkv/proj use As+Ws (18432 B); attn aliases the same block (Pb+psum).
// ---------------------------------------------------------------------------
__global__ __launch_bounds__(256, 4)
void mega(const float* __restrict__ x, const float* __restrict__ qkv_w,
          const float* __restrict__ qkv_b, const float* __restrict__ proj_w,
          const float* __restrict__ proj_b, float* __restrict__ out,
          unsigned short* __restrict__ xb, unsigned short* __restrict__ wqb,
          unsigned short* __restrict__ pwb, unsigned short* __restrict__ qb,
          unsigned short* __restrict__ kb, unsigned short* __restrict__ vtb,
          unsigned short* __restrict__ aob, unsigned* bar)
{
    __shared__ __align__(16) unsigned short SM[2 * 64 * GLD];   // 18432 B
    unsigned short* As = SM;
    unsigned short* Ws = SM + 64 * GLD;
    unsigned short* Pb = SM;                                    // 14848 B used
    float (*psum)[32] = (float (*)[32])(SM + 32 * PST);         // 256 B @14848

    const int t    = threadIdx.x;
    const int lane = t & 63;
    const int wave = t >> 6;
    const int fm   = lane & 15;
    const int fq   = lane >> 4;
    const int srow = t >> 2;
    const int scol = (t & 3) * 16;
    const int wm   = (wave & 1) * 32;
    const int wn   = (wave >> 1) * 32;

    // ---------------- Phase 0: fp32 -> bf16 casts -------------------------
    for (int uu = blockIdx.x; uu < CAST_UNITS; uu += GRID) {
        int i = (uu * 256 + t) * 8;
        const float* src; unsigned short* dst;
        if (i < NX)            { src = x      + i;             dst = xb  + i; }
        else if (i < NX + NQ)  { src = qkv_w  + (i - NX);      dst = wqb + (i - NX); }
        else                   { src = proj_w + (i - NX - NQ); dst = pwb + (i - NX - NQ); }
        float4 f0 = *(const float4*)src;
        float4 f1 = *(const float4*)(src + 4);
        U4B8 uo;
        uo.s[0] = f2bf(f0.x); uo.s[1] = f2bf(f0.y); uo.s[2] = f2bf(f0.z); uo.s[3] = f2bf(f0.w);
        uo.s[4] = f2bf(f1.x); uo.s[5] = f2bf(f1.y); uo.s[6] = f2bf(f1.z); uo.s[7] = f2bf(f1.w);
        *(uint4*)dst = uo.u;
    }
    grid_barrier(bar);

    // ---------------- Phase 1: QKV GEMM (64x64 tile, BK=64) ---------------
    for (int tile = blockIdx.x; tile < QKV_TILES; tile += GRID) {
        const int m0 = (tile & 127) * 64;
        const int j0 = (tile >> 7) * 64;

        f32x4 acc[2][2];
        #pragma unroll
        for (int i = 0; i < 2; i++)
            #pragma unroll
            for (int j = 0; j < 2; j++)
                acc[i][j] = (f32x4){0.f, 0.f, 0.f, 0.f};

        const unsigned short* Arow = xb  + (size_t)(m0 + srow) * Es;
        const unsigned short* Wrow = wqb + (size_t)(j0 + srow) * Es;

        for (int k0 = 0; k0 < Es; k0 += 64) {
            uint4 a0 = *(const uint4*)(Arow + k0 + scol);
            uint4 a1 = *(const uint4*)(Arow + k0 + scol + 8);
            uint4 w0 = *(const uint4*)(Wrow + k0 + scol);
            uint4 w1 = *(const uint4*)(Wrow + k0 + scol + 8);
            __syncthreads();
            *(uint4*)&As[srow * GLD + scol]     = a0;
            *(uint4*)&As[srow * GLD + scol + 8] = a1;
            *(uint4*)&Ws[srow * GLD + scol]     = w0;
            *(uint4*)&Ws[srow * GLD + scol + 8] = w1;
            __syncthreads();
            #pragma unroll
            for (int ks = 0; ks < 64; ks += 32) {
                U4B8 af0, af1, bf0, bf1;
                af0.u = *(const uint4*)&As[(wm +      fm) * GLD + ks + fq * 8];
                af1.u = *(const uint4*)&As[(wm + 16 + fm) * GLD + ks + fq * 8];
                bf0.u = *(const uint4*)&Ws[(wn +      fm) * GLD + ks + fq * 8];
                bf1.u = *(const uint4*)&Ws[(wn + 16 + fm) * GLD + ks + fq * 8];
                acc[0][0] = __builtin_amdgcn_mfma_f32_16x16x32_bf16(af0.b, bf0.b, acc[0][0], 0, 0, 0);
                acc[0][1] = __builtin_amdgcn_mfma_f32_16x16x32_bf16(af0.b, bf1.b, acc[0][1], 0, 0, 0);
                acc[1][0] = __builtin_amdgcn_mfma_f32_16x16x32_bf16(af1.b, bf0.b, acc[1][0], 0, 0, 0);
                acc[1][1] = __builtin_amdgcn_mfma_f32_16x16x32_bf16(af1.b, bf1.b, acc[1][1], 0, 0, 0);
            }
        }

        // C/D: col = lane&15, row = quad*4 + reg
        #pragma unroll
        for (int mt = 0; mt < 2; mt++) {
            #pragma unroll
            for (int nt = 0; nt < 2; nt++) {
                #pragma unroll
                for (int r = 0; r < 4; r++) {
                    int row = m0 + wm + mt * 16 + fq * 4 + r;
                    int col = j0 + wn + nt * 16 + fm;
                    float val = acc[mt][nt][r] + qkv_b[col];
                    int part = col >> 8;           // 0:q 1:k 2:v
                    int head = (col >> 5) & 7;
                    int d = col & 31;
                    int b = row >> 10;
                    int n = row & 1023;
                    int bh = b * NH + head;
                    if (part == 0)
                        qb[((size_t)bh * Ns + n) * DH + d] = f2bf(val * 0.0625f);
                    else if (part == 1)
                        kb[((size_t)bh * Ns + n) * DH + d] = f2bf(val);
                    else
                        vtb[((size_t)bh * DH + d) * Ns + n] = f2bf(val);
                }
            }
        }
    }
    grid_barrier(bar);

    // ---------------- Phase 2: MFMA attention (no-max-shift softmax) ------
    for (int blk = blockIdx.x; blk < ATTN_TILES; blk += GRID) {
        const int b  = blk & 7;
        const int u2 = blk >> 3;
        const int h  = u2 & 7;
        const int hq = u2 >> 3;
        const int bh = b * NH + h;

        __syncthreads();                   // Pb/psum reuse across tile loop

        int n0c = (hq - 3) * 32;
        n0c = n0c < 0 ? 0 : (n0c > Ns - 224 ? Ns - 224 : n0c);

        const int qbase = (wave & 1) * 16;   // query 16-tile
        const int sel   = wave >> 1;         // key-tile parity
        const int dbase = (wave >> 1) * 16;  // PV dim-tile

        // V^T fragment prefetch (B-operand: n=dim, k=key)
        const unsigned short* vrow = vtb + ((size_t)bh * DH + dbase + fm) * Ns;
        uint4 vpre[7];
        #pragma unroll
        for (int i = 0; i < 7; i++)
            vpre[i] = *(const uint4*)(vrow + n0c + i * 32 + fq * 8);

        // Q fragment (A-operand)
        U4B8 qa;
        qa.u = *(const uint4*)(qb + ((size_t)bh * Ns + hq * 32 + qbase + fm) * DH + fq * 8);

        // S = Q.K^T (key = kt*16+fm, query = qbase+fq*4+r)
        f32x4 sv[7];
        #pragma unroll
        for (int i = 0; i < 7; i++) {
            int kt = sel + 2 * i;
            U4B8 kf;
            kf.u = *(const uint4*)(kb + ((size_t)bh * Ns + n0c + kt * 16 + fm) * DH + fq * 8);
            sv[i] = __builtin_amdgcn_mfma_f32_16x16x32_bf16(qa.b, kf.b, (f32x4){0.f,0.f,0.f,0.f}, 0, 0, 0);
        }

        // mask + exp (no max shift) + P write + local sum of rounded values
        float sm[4] = {0.f, 0.f, 0.f, 0.f};
        #pragma unroll
        for (int i = 0; i < 7; i++) {
            int kt = sel + 2 * i;
            int g = n0c + kt * 16 + fm;          // absolute key token
            int gh = g >> 5, gw = g & 31;
            int dhh = gh - hq;
            bool okh = (dhh >= -3) && (dhh <= 3);
            #pragma unroll
            for (int r = 0; r < 4; r++) {
                int qc = qbase + fq * 4 + r;
                int dww = gw - qc;
                bool ok = okh && (dww >= -5) && (dww <= 5);
                float p = ok ? __expf(sv[i][r]) : 0.f;
                unsigned short pu = f2bf(p);
                Pb[qc * PST + kt * 16 + fm] = pu;
                sm[r] += bf2f(pu);
            }
        }
        #pragma unroll
        for (int r = 0; r < 4; r++)
            #pragma unroll
            for (int m = 1; m < 16; m <<= 1)
                sm[r] += __shfl_xor(sm[r], m);
        if (fm == 0) {
            #pragma unroll
            for (int r = 0; r < 4; r++)
                psum[sel][qbase + fq * 4 + r] = sm[r];
        }
        __syncthreads();   // P complete + psum visible

        // O = P.V
        f32x4 acc = (f32x4){0.f, 0.f, 0.f, 0.f};
        #pragma unroll
        for (int i = 0; i < 7; i++) {
            U4B8 pa, vb;
            pa.u = *(const uint4*)&Pb[(qbase + fm) * PST + i * 32 + fq * 8];
            vb.u = vpre[i];
            acc = __builtin_amdgcn_mfma_f32_16x16x32_bf16(pa.b, vb.b, acc, 0, 0, 0);
        }

        #pragma unroll
        for (int r = 0; r < 4; r++) {
            int qq = qbase + fq * 4 + r;
            float inv = 1.f / (psum[0][qq] + psum[1][qq]);
            aob[((size_t)(b * Ns) + hq * 32 + qq) * Es + h * DH + dbase + fm] = f2bf(acc[r] * inv);
        }
    }
    grid_barrier(bar);

    // ---------------- Phase 3: proj GEMM (bf16 in, fp32 out) --------------
    for (int tile = blockIdx.x; tile < PROJ_TILES; tile += GRID) {
        const int m0 = (tile & 127) * 64;
        const int j0 = (tile >> 7) * 64;

        f32x4 acc[2][2];
        #pragma unroll
        for (int i = 0; i < 2; i++)
            #pragma unroll
            for (int j = 0; j < 2; j++)
                acc[i][j] = (f32x4){0.f, 0.f, 0.f, 0.f};

        const unsigned short* Arow = aob + (size_t)(m0 + srow) * Es;
        const unsigned short* Wrow = pwb + (size_t)(j0 + srow) * Es;

        for (int k0 = 0; k0 < Es; k0 += 64) {
            uint4 a0 = *(const uint4*)(Arow + k0 + scol);
            uint4 a1 = *(const uint4*)(Arow + k0 + scol + 8);
            uint4 w0 = *(const uint4*)(Wrow + k0 + scol);
            uint4 w1 = *(const uint4*)(Wrow + k0 + scol + 8);
            __syncthreads();
            *(uint4*)&As[srow * GLD + scol]     = a0;
            *(uint4*)&As[srow * GLD + scol + 8] = a1;
            *(uint4*)&Ws[srow * GLD + scol]     = w0;
            *(uint4*)&Ws[srow * GLD + scol + 8] = w1;
            __syncthreads();
            #pragma unroll
            for (int ks = 0; ks < 64; ks += 32) {
                U4B8 af0, af1, bf0, bf1;
                af0.u = *(const uint4*)&As[(wm +      fm) * GLD + ks + fq * 8];
                af1.u = *(const uint4*)&As[(wm + 16 + fm) * GLD + ks + fq * 8];
                bf0.u = *(const uint4*)&Ws[(wn +      fm) * GLD + ks + fq * 8];
                bf1.u = *(const uint4*)&Ws[(wn + 16 + fm) * GLD + ks + fq * 8];
                acc[0][0] = __builtin_amdgcn_mfma_f32_16x16x32_bf16(af0.b, bf0.b, acc[0][0], 0, 0, 0);
                acc[0][1] = __builtin_amdgcn_mfma_f32_16x16x32_bf16(af0.b, bf1.b, acc[0][1], 0, 0, 0);
                acc[1][0] = __builtin_amdgcn_mfma_f32_16x16x32_bf16(af1.b, bf0.b, acc[1][0], 0, 0, 0);
                acc[1][1] = __builtin_amdgcn_mfma_f32_16x16x32_bf16(af1.b, bf1.b, acc[1][1], 0, 0, 0);
            }
        }

        #pragma unroll
        for (int mt = 0; mt < 2; mt++) {
            #pragma unroll
            for (int nt = 0; nt < 2; nt++) {
                #pragma unroll
                for (int r = 0; r < 4; r++) {
                    int row = m0 + wm + mt * 16 + fq * 4 + r;
                    int col = j0 + wn + nt * 16 + fm;
                    out[(size_t)row * Es + col] = acc[mt][nt][r] + proj_b[col];
                }
            }
        }
    }
}

extern "C" void kernel_launch(void* const* d_in, const int* in_sizes, int n_in,
                              void* d_out, int out_size, void* d_ws, size_t ws_size,
                              hipStream_t stream) {
    const float* x      = (const float*)d_in[0];  // [B,N,E]
    const float* qkv_w  = (const float*)d_in[1];  // [3E,E]
    const float* qkv_b  = (const float*)d_in[2];  // [3E]
    const float* proj_w = (const float*)d_in[3];  // [E,E]
    const float* proj_b = (const float*)d_in[4];  // [E]
    float* out = (float*)d_out;                   // [B,N,E]

    unsigned short* xb  = (unsigned short*)d_ws;  // NX bf16
    unsigned short* wqb = xb + NX;                // NQ bf16
    unsigned short* pwb = wqb + NQ;               // NP bf16
    unsigned short* qb  = pwb + NP;               // NX bf16 (q, scaled)
    unsigned short* kb  = qb + NX;                // NX bf16
    unsigned short* vtb = kb + NX;                // NX bf16 (transposed)
    unsigned short* aob = vtb + NX;               // NX bf16 (attn out)
    unsigned* bar = (unsigned*)(aob + NX + 64);   // barrier region (1280 B)

    // Zero barrier state every launch (inside the graph): poison-proof.
    hipMemsetAsync(bar, 0, (288 + 32) * sizeof(unsigned), stream);

    mega<<<dim3(GRID), dim3(256), 0, stream>>>(
        x, qkv_w, qkv_b, proj_w, proj_b, out,
        xb, wqb, pwb, qb, kb, vtb, aob, bar);
}

// Round 4
// 100.434 us; speedup vs baseline: 4.6879x; 4.6879x over previous
//
#include <hip/hip_runtime.h>
#include <math.h>

// Problem constants
constexpr int Bb = 8;     // batch
constexpr int Ns = 1024;  // tokens (32x32)
constexpr int Es = 256;   // embed
constexpr int NH = 8;     // heads
constexpr int DH = 32;    // head dim
constexpr int Mrows = Bb * Ns;        // 8192
constexpr int NX = Mrows * Es;        // 2097152
constexpr int NQ = 3 * Es * Es;       // 196608
constexpr int NP = Es * Es;           // 65536

typedef __bf16 bf16x8 __attribute__((ext_vector_type(8)));
typedef float  f32x4  __attribute__((ext_vector_type(4)));
union U4B8 { uint4 u; bf16x8 b; unsigned short s[8]; };

__device__ __forceinline__ unsigned short f2bf(float f) {
    union { float f; unsigned u; } c; c.f = f;
    unsigned r = (c.u + 0x7FFFu + ((c.u >> 16) & 1u)) >> 16;
    return (unsigned short)r;
}
__device__ __forceinline__ float bf2f(unsigned short h) {
    union { unsigned u; float f; } c; c.u = ((unsigned)h) << 16;
    return c.f;
}

#define GLD 72    // gemm LDS row stride (bf16)
#define PST 232   // attn P row stride (bf16)

// ---------------------------------------------------------------------------
// R2/R3 post-mortem: persistent mega-kernel with device-scope grid barriers
// costs 60-110us PER BARRIER on MI355X (acquire-poll storm through the
// coherence point; 512 pollers -> 67us, 1024 pollers -> 110us). Abandoned.
// This is the verified 4-kernel baseline (101us) with ONE change: occupancy.
// R2's union kernel (all 4 phases in one function) compiled to 56 VGPR ->
// each phase fits well under a 64-VGPR cap -> (256,8) = 8 blocks/CU for the
// GEMMs/cast, (256,6) (85-VGPR cap) for attn whose live set is ~80.
// Phases are latency-bound (MfmaUtil <1%, VALUBusy <3%): more waves = the fix.
// ---------------------------------------------------------------------------

// Kernel 0: cast x, qkv_w, proj_w fp32 -> bf16 once. 8 elems/thread.
__global__ __launch_bounds__(256, 8)
void cast_all(const float* __restrict__ x, const float* __restrict__ wq,
              const float* __restrict__ wp, unsigned short* __restrict__ xb,
              unsigned short* __restrict__ wqb, unsigned short* __restrict__ wpb)
{
    int i = (blockIdx.x * 256 + threadIdx.x) * 8;
    const float* src; unsigned short* dst;
    if (i < NX)            { src = x  + i;             dst = xb  + i; }
    else if (i < NX + NQ)  { src = wq + (i - NX);      dst = wqb + (i - NX); }
    else                   { src = wp + (i - NX - NQ); dst = wpb + (i - NX - NQ); }
    float4 f0 = *(const float4*)src;
    float4 f1 = *(const float4*)(src + 4);
    U4B8 u;
    u.s[0] = f2bf(f0.x); u.s[1] = f2bf(f0.y); u.s[2] = f2bf(f0.z); u.s[3] = f2bf(f0.w);
    u.s[4] = f2bf(f1.x); u.s[5] = f2bf(f1.y); u.s[6] = f2bf(f1.z); u.s[7] = f2bf(f1.w);
    *(uint4*)dst = u.u;
}

// ---------------------------------------------------------------------------
// Kernel 1: QKV GEMM (R8-verified shape — 64x64 tile, BK=64). Now 8 blocks/CU.
// ---------------------------------------------------------------------------
__global__ __launch_bounds__(256, 8)
void qkv_gemm(const unsigned short* __restrict__ A, const unsigned short* __restrict__ W,
              const float* __restrict__ qkv_b,
              unsigned short* __restrict__ qo, unsigned short* __restrict__ ko,
              unsigned short* __restrict__ vto)
{
    __shared__ unsigned short As[64 * GLD];
    __shared__ unsigned short Ws[64 * GLD];

    const int t = threadIdx.x;
    const int m0 = (blockIdx.x & 127) * 64;
    const int j0 = (blockIdx.x >> 7) * 64;

    const int srow = t >> 2;
    const int scol = (t & 3) * 16;

    const int lane = t & 63;
    const int wave = t >> 6;
    const int wm = (wave & 1) * 32;
    const int wn = (wave >> 1) * 32;
    const int fm = lane & 15;
    const int fq = lane >> 4;

    f32x4 acc[2][2];
    #pragma unroll
    for (int i = 0; i < 2; i++)
        #pragma unroll
        for (int j = 0; j < 2; j++)
            acc[i][j] = (f32x4){0.f, 0.f, 0.f, 0.f};

    const unsigned short* Arow = A + (size_t)(m0 + srow) * Es;
    const unsigned short* Wrow = W + (size_t)(j0 + srow) * Es;

    for (int k0 = 0; k0 < Es; k0 += 64) {
        uint4 a0 = *(const uint4*)(Arow + k0 + scol);
        uint4 a1 = *(const uint4*)(Arow + k0 + scol + 8);
        uint4 w0 = *(const uint4*)(Wrow + k0 + scol);
        uint4 w1 = *(const uint4*)(Wrow + k0 + scol + 8);
        __syncthreads();
        *(uint4*)&As[srow * GLD + scol]     = a0;
        *(uint4*)&As[srow * GLD + scol + 8] = a1;
        *(uint4*)&Ws[srow * GLD + scol]     = w0;
        *(uint4*)&Ws[srow * GLD + scol + 8] = w1;
        __syncthreads();
        #pragma unroll
        for (int ks = 0; ks < 64; ks += 32) {
            U4B8 af0, af1, bf0, bf1;
            af0.u = *(const uint4*)&As[(wm +      fm) * GLD + ks + fq * 8];
            af1.u = *(const uint4*)&As[(wm + 16 + fm) * GLD + ks + fq * 8];
            bf0.u = *(const uint4*)&Ws[(wn +      fm) * GLD + ks + fq * 8];
            bf1.u = *(const uint4*)&Ws[(wn + 16 + fm) * GLD + ks + fq * 8];
            acc[0][0] = __builtin_amdgcn_mfma_f32_16x16x32_bf16(af0.b, bf0.b, acc[0][0], 0, 0, 0);
            acc[0][1] = __builtin_amdgcn_mfma_f32_16x16x32_bf16(af0.b, bf1.b, acc[0][1], 0, 0, 0);
            acc[1][0] = __builtin_amdgcn_mfma_f32_16x16x32_bf16(af1.b, bf0.b, acc[1][0], 0, 0, 0);
            acc[1][1] = __builtin_amdgcn_mfma_f32_16x16x32_bf16(af1.b, bf1.b, acc[1][1], 0, 0, 0);
        }
    }

    // C/D: col = lane&15, row = quad*4 + reg
    #pragma unroll
    for (int mt = 0; mt < 2; mt++) {
        #pragma unroll
        for (int nt = 0; nt < 2; nt++) {
            #pragma unroll
            for (int r = 0; r < 4; r++) {
                int row = m0 + wm + mt * 16 + fq * 4 + r;
                int col = j0 + wn + nt * 16 + fm;
                float val = acc[mt][nt][r] + qkv_b[col];
                int part = col >> 8;           // 0:q 1:k 2:v
                int head = (col >> 5) & 7;
                int d = col & 31;
                int b = row >> 10;
                int n = row & 1023;
                int bh = b * NH + head;
                if (part == 0)
                    qo[((size_t)bh * Ns + n) * DH + d] = f2bf(val * 0.0625f);
                else if (part == 1)
                    ko[((size_t)bh * Ns + n) * DH + d] = f2bf(val);
                else
                    vto[((size_t)bh * DH + d) * Ns + n] = f2bf(val);
            }
        }
    }
}

// ---------------------------------------------------------------------------
// Kernel 2: MFMA attention, in-register softmax WITHOUT max-subtraction.
// (256,6): 85-VGPR cap — live set vpre[7]+sv[7]+qa ~ 80, 6 blocks/CU.
// ---------------------------------------------------------------------------
__global__ __launch_bounds__(256, 6)
void attn_mfma2(const unsigned short* __restrict__ qb, const unsigned short* __restrict__ kb,
                const unsigned short* __restrict__ vtb, unsigned short* __restrict__ aob)
{
    __shared__ unsigned short Pb[32 * PST];   // 14848 B
    __shared__ float psum[2][32];

    const int blk = blockIdx.x;          // 0..2047
    const int b   = blk & 7;             // XCD-locality: batch pinned to XCD
    const int u   = blk >> 3;
    const int h   = u & 7;
    const int hq  = u >> 3;
    const int bh  = b * NH + h;

    const int t   = threadIdx.x;
    const int lane = t & 63;
    const int w    = t >> 6;
    const int fm = lane & 15;
    const int fq = lane >> 4;

    int n0c = (hq - 3) * 32;
    n0c = n0c < 0 ? 0 : (n0c > Ns - 224 ? Ns - 224 : n0c);

    const int qbase = (w & 1) * 16;      // query 16-tile
    const int sel   = w >> 1;            // key-tile parity
    const int dbase = (w >> 1) * 16;     // PV dim-tile

    // V^T fragment prefetch (B-operand: n=dim, k=key)
    const unsigned short* vrow = vtb + ((size_t)bh * DH + dbase + fm) * Ns;
    uint4 vpre[7];
    #pragma unroll
    for (int i = 0; i < 7; i++)
        vpre[i] = *(const uint4*)(vrow + n0c + i * 32 + fq * 8);

    // Q fragment (A-operand)
    U4B8 qa;
    qa.u = *(const uint4*)(qb + ((size_t)bh * Ns + hq * 32 + qbase + fm) * DH + fq * 8);

    // S = Q.K^T in C-layout registers (key = kt*16+fm, query = qbase+fq*4+r)
    f32x4 sv[7];
    #pragma unroll
    for (int i = 0; i < 7; i++) {
        int kt = sel + 2 * i;
        U4B8 kf;
        kf.u = *(const uint4*)(kb + ((size_t)bh * Ns + n0c + kt * 16 + fm) * DH + fq * 8);
        sv[i] = __builtin_amdgcn_mfma_f32_16x16x32_bf16(qa.b, kf.b, (f32x4){0.f,0.f,0.f,0.f}, 0, 0, 0);
    }

    // mask + exp (no max shift) + P write + local sum of rounded values
    float sm[4] = {0.f, 0.f, 0.f, 0.f};
    #pragma unroll
    for (int i = 0; i < 7; i++) {
        int kt = sel + 2 * i;
        int g = n0c + kt * 16 + fm;          // absolute key token
        int gh = g >> 5, gw = g & 31;
        int dhh = gh - hq;
        bool okh = (dhh >= -3) && (dhh <= 3);
        #pragma unroll
        for (int r = 0; r < 4; r++) {
            int qc = qbase + fq * 4 + r;
            int dww = gw - qc;
            bool ok = okh && (dww >= -5) && (dww <= 5);
            float p = ok ? __expf(sv[i][r]) : 0.f;
            unsigned short pu = f2bf(p);
            Pb[qc * PST + kt * 16 + fm] = pu;
            sm[r] += bf2f(pu);
        }
    }
    #pragma unroll
    for (int r = 0; r < 4; r++)
        #pragma unroll
        for (int m = 1; m < 16; m <<= 1)
            sm[r] += __shfl_xor(sm[r], m);
    if (fm == 0) {
        #pragma unroll
        for (int r = 0; r < 4; r++)
            psum[sel][qbase + fq * 4 + r] = sm[r];
    }
    __syncthreads();   // P complete + psum visible (single barrier)

    // O = P.V
    f32x4 acc = (f32x4){0.f, 0.f, 0.f, 0.f};
    #pragma unroll
    for (int i = 0; i < 7; i++) {
        U4B8 pa, vb;
        pa.u = *(const uint4*)&Pb[(qbase + fm) * PST + i * 32 + fq * 8];
        vb.u = vpre[i];
        acc = __builtin_amdgcn_mfma_f32_16x16x32_bf16(pa.b, vb.b, acc, 0, 0, 0);
    }

    #pragma unroll
    for (int r = 0; r < 4; r++) {
        int qq = qbase + fq * 4 + r;
        float inv = 1.f / (psum[0][qq] + psum[1][qq]);
        aob[((size_t)(b * Ns) + hq * 32 + qq) * Es + h * DH + dbase + fm] = f2bf(acc[r] * inv);
    }
}

// ---------------------------------------------------------------------------
// Kernel 3: proj GEMM (R8-verified shape). bf16 in, fp32 out. Now 8 blocks/CU.
// ---------------------------------------------------------------------------
__global__ __launch_bounds__(256, 8)
void proj_gemm(const unsigned short* __restrict__ A, const unsigned short* __restrict__ Wb,
               const float* __restrict__ bias, float* __restrict__ out)
{
    __shared__ unsigned short As[64 * GLD];
    __shared__ unsigned short Ws[64 * GLD];

    const int t = threadIdx.x;
    const int m0 = (blockIdx.x & 127) * 64;
    const int j0 = (blockIdx.x >> 7) * 64;

    const int srow = t >> 2;
    const int scol = (t & 3) * 16;

    const int lane = t & 63;
    const int wave = t >> 6;
    const int wm = (wave & 1) * 32;
    const int wn = (wave >> 1) * 32;
    const int fm = lane & 15;
    const int fq = lane >> 4;

    f32x4 acc[2][2];
    #pragma unroll
    for (int i = 0; i < 2; i++)
        #pragma unroll
        for (int j = 0; j < 2; j++)
            acc[i][j] = (f32x4){0.f, 0.f, 0.f, 0.f};

    const unsigned short* Arow = A + (size_t)(m0 + srow) * Es;
    const unsigned short* Wrow = Wb + (size_t)(j0 + srow) * Es;

    for (int k0 = 0; k0 < Es; k0 += 64) {
        uint4 a0 = *(const uint4*)(Arow + k0 + scol);
        uint4 a1 = *(const uint4*)(Arow + k0 + scol + 8);
        uint4 w0 = *(const uint4*)(Wrow + k0 + scol);
        uint4 w1 = *(const uint4*)(Wrow + k0 + scol + 8);
        __syncthreads();
        *(uint4*)&As[srow * GLD + scol]     = a0;
        *(uint4*)&As[srow * GLD + scol + 8] = a1;
        *(uint4*)&Ws[srow * GLD + scol]     = w0;
        *(uint4*)&Ws[srow * GLD + scol + 8] = w1;
        __syncthreads();
        #pragma unroll
        for (int ks = 0; ks < 64; ks += 32) {
            U4B8 af0, af1, bf0, bf1;
            af0.u = *(const uint4*)&As[(wm +      fm) * GLD + ks + fq * 8];
            af1.u = *(const uint4*)&As[(wm + 16 + fm) * GLD + ks + fq * 8];
            bf0.u = *(const uint4*)&Ws[(wn +      fm) * GLD + ks + fq * 8];
            bf1.u = *(const uint4*)&Ws[(wn + 16 + fm) * GLD + ks + fq * 8];
            acc[0][0] = __builtin_amdgcn_mfma_f32_16x16x32_bf16(af0.b, bf0.b, acc[0][0], 0, 0, 0);
            acc[0][1] = __builtin_amdgcn_mfma_f32_16x16x32_bf16(af0.b, bf1.b, acc[0][1], 0, 0, 0);
            acc[1][0] = __builtin_amdgcn_mfma_f32_16x16x32_bf16(af1.b, bf0.b, acc[1][0], 0, 0, 0);
            acc[1][1] = __builtin_amdgcn_mfma_f32_16x16x32_bf16(af1.b, bf1.b, acc[1][1], 0, 0, 0);
        }
    }

    #pragma unroll
    for (int mt = 0; mt < 2; mt++) {
        #pragma unroll
        for (int nt = 0; nt < 2; nt++) {
            #pragma unroll
            for (int r = 0; r < 4; r++) {
                int row = m0 + wm + mt * 16 + fq * 4 + r;
                int col = j0 + wn + nt * 16 + fm;
                out[(size_t)row * Es + col] = acc[mt][nt][r] + bias[col];
            }
        }
    }
}

extern "C" void kernel_launch(void* const* d_in, const int* in_sizes, int n_in,
                              void* d_out, int out_size, void* d_ws, size_t ws_size,
                              hipStream_t stream) {
    const float* x      = (const float*)d_in[0];  // [B,N,E]
    const float* qkv_w  = (const float*)d_in[1];  // [3E,E]
    const float* qkv_b  = (const float*)d_in[2];  // [3E]
    const float* proj_w = (const float*)d_in[3];  // [E,E]
    const float* proj_b = (const float*)d_in[4];  // [E]
    float* out = (float*)d_out;                   // [B,N,E]

    unsigned short* xb  = (unsigned short*)d_ws;  // NX bf16
    unsigned short* wqb = xb + NX;                // NQ bf16
    unsigned short* pwb = wqb + NQ;               // NP bf16
    unsigned short* qb  = pwb + NP;               // NX bf16 (q, scaled)
    unsigned short* kb  = qb + NX;                // NX bf16
    unsigned short* vtb = kb + NX;                // NX bf16 (transposed)
    unsigned short* aob = vtb + NX;               // NX bf16 (attn out)

    cast_all<<<dim3((NX + NQ + NP) / 8 / 256), dim3(256), 0, stream>>>(
        x, qkv_w, proj_w, xb, wqb, pwb);

    qkv_gemm<<<dim3(1536), dim3(256), 0, stream>>>(xb, wqb, qkv_b, qb, kb, vtb);

    attn_mfma2<<<dim3(Bb * NH * 32), dim3(256), 0, stream>>>(qb, kb, vtb, aob);

    proj_gemm<<<dim3(128 * 4), dim3(256), 0, stream>>>(aob, pwb, proj_b, out);
}